// Round 8
// baseline (594.350 us; speedup 1.0000x reference)
//
#include <hip/hip_runtime.h>
#include <hip/hip_bf16.h>

typedef __bf16 bf16_t;
typedef __attribute__((ext_vector_type(4))) __bf16 bf16x4;
typedef __attribute__((ext_vector_type(8))) __bf16 bf16x8;
typedef __attribute__((ext_vector_type(4))) float f32x4;

#define DIM 128
#define GTILE 32

// async global->LDS, 16B per lane. LDS dest = wave-uniform base + lane*16.
__device__ __forceinline__ void gl_lds16(const void* g, void* l) {
    __builtin_amdgcn_global_load_lds(
        (const __attribute__((address_space(1))) unsigned int*)g,
        (__attribute__((address_space(3))) unsigned int*)l, 16, 0, 0);
}

// ---- merged weight-prep + degree count + f32->bf16 input convert (independent) ----
__global__ void prep_count(const float* __restrict__ Wl, const float* __restrict__ Wr,
                           bf16_t* __restrict__ Wc,
                           const int* __restrict__ dA, int* __restrict__ cA,
                           const int* __restrict__ dB, int* __restrict__ cB, int E,
                           const float* __restrict__ xm, bf16_t* __restrict__ xbm, int CM,
                           const float* __restrict__ xt, bf16_t* __restrict__ xbt, int CT,
                           int PB, int CB) {
    int blk = blockIdx.x;
    if (blk < PB) {
        int idx = blk * 256 + threadIdx.x;           // over 6*128*256
        if (idx >= 6 * 128 * 256) return;
        int k = idx & 255;
        int n = (idx >> 8) & 127;
        int s = idx >> 15;                            // 0..5
        float v;
        if (k < 128) v = Wl[((size_t)s * 128 + n) * 128 + k];
        else         v = Wr[((size_t)s * 128 + n) * 128 + (k - 128)];
        Wc[idx] = (bf16_t)v;
    } else if (blk < PB + CB) {
        int i = (blk - PB) * 256 + threadIdx.x;
        if (i < E) atomicAdd(&cA[dA[i]], 1);
        else if (i < 2 * E) atomicAdd(&cB[dB[i - E]], 1);
    } else {
        int i = (blk - PB - CB) * 256 + threadIdx.x;  // chunk of 8 elems
        const float* src; bf16_t* dst;
        if (i < CM) { src = xm; dst = xbm; }
        else if ((i -= CM) < CT) { src = xt; dst = xbt; }
        else return;
        float4 a = ((const float4*)src)[(size_t)i * 2];
        float4 b = ((const float4*)src)[(size_t)i * 2 + 1];
        bf16x8 r;
        r[0] = (bf16_t)a.x; r[1] = (bf16_t)a.y; r[2] = (bf16_t)a.z; r[3] = (bf16_t)a.w;
        r[4] = (bf16_t)b.x; r[5] = (bf16_t)b.y; r[6] = (bf16_t)b.z; r[7] = (bf16_t)b.w;
        *(bf16x8*)(dst + (size_t)i * 8) = r;
    }
}

// ---- single-dispatch exclusive scan: block 0 = side A, block 1 = side B ----
// 1024 threads, hierarchical shfl scan; writes rowstart (M+1 entries, rs[M]=total)
// and cursor (M entries). Replaces scan_local2 + scan_blocks2 + add_offsets2.
__global__ __launch_bounds__(1024) void scan_all(
    const int* __restrict__ cntA, int* __restrict__ rsA, int* __restrict__ curA, int MA,
    const int* __restrict__ cntB, int* __restrict__ rsB, int* __restrict__ curB, int MB) {
    const int* cnt; int* rs; int* cur; int M;
    if (blockIdx.x == 0) { cnt = cntA; rs = rsA; cur = curA; M = MA; }
    else                 { cnt = cntB; rs = rsB; cur = curB; M = MB; }
    __shared__ int swv[16];
    __shared__ int srun;
    const int tid  = threadIdx.x;
    const int wave = tid >> 6;
    const int lane = tid & 63;
    if (tid == 0) srun = 0;
    __syncthreads();
    for (int base = 0; base < M; base += 1024) {
        int i = base + tid;
        int v = (i < M) ? cnt[i] : 0;
        int x = v;
#pragma unroll
        for (int off = 1; off < 64; off <<= 1) {
            int t = __shfl_up(x, off, 64);
            if (lane >= off) x += t;
        }
        if (lane == 63) swv[wave] = x;
        __syncthreads();
        if (wave == 0) {                           // whole wave 0 scans the 16 sums
            int y = (lane < 16) ? swv[lane] : 0;
#pragma unroll
            for (int off = 1; off < 16; off <<= 1) {
                int t = __shfl_up(y, off, 64);
                if (lane >= off) y += t;
            }
            if (lane < 16) swv[lane] = y;
        }
        __syncthreads();
        int r = srun;
        int excl = x - v + (wave ? swv[wave - 1] : 0) + r;
        if (i < M) { rs[i] = excl; cur[i] = excl; }
        __syncthreads();                           // all read srun/swv before update
        if (tid == 0) srun = r + swv[15];
        __syncthreads();
    }
    if (threadIdx.x == 0) rs[M] = srun;            // = total edge count
}

__global__ void bin_edges2(const int* __restrict__ sA, const int* __restrict__ dA,
                           int* __restrict__ curA, int* __restrict__ csrA,
                           const int* __restrict__ sB, const int* __restrict__ dB,
                           int* __restrict__ curB, int* __restrict__ csrB, int E) {
    int e = blockIdx.x * blockDim.x + threadIdx.x;
    if (e < E) {
        int d = dA[e];
        int pos = atomicAdd(&curA[d], 1);
        csrA[pos] = sA[e];
    } else if (e < 2 * E) {
        int i = e - E;
        int d = dB[i];
        int pos = atomicAdd(&curB[d], 1);
        csrB[pos] = sB[i];
    }
}

// ---------------- fused gather-mean + GEMM, persistent, both sides --------------
// All inputs bf16. Per 32-row tile: gather phase computes mean of neighbor bf16
// rows (f32 accumulate) directly into the swizzled A0 LDS buffer; A1 (x_dst,
// bf16) prefetched via global_load_lds double-buffer (hidden under gather);
// then MFMA: out = A0@Wl.T + bias + A1@Wr.T (+ReLU).
// MODE 1: out bf16 + relu.  MODE 2: out f32, no relu.
// Gather: rows processed in PAIRS with exact batch-4 per row (8 independent
// loads in flight, ~36% fewer requests + serial steps than clamp-8). Per-row
// summation order (even k->acc0, odd k->acc1, ascending) is bit-identical to
// the previous batch-8 version. Degree n = rs[d+1]-rs[d] (rs has M+1 entries).
// __launch_bounds__(256,3): (256,5) proved to spill breg (round 6, +236MB HBM).
#define A0SZ 8192               // 32 rows * 256B bf16
#define A1SZ 8192               // 32 rows * 256B bf16

template <int MODE>
__global__ __launch_bounds__(256, 3) void fused2(
    const bf16_t* __restrict__ gsA, const int* __restrict__ rsA,
    const int* __restrict__ csA,
    const bf16_t* __restrict__ a1A, const bf16_t* __restrict__ WcA,
    const float* __restrict__ bA, void* __restrict__ oA, int Ma,
    const bf16_t* __restrict__ gsB, const int* __restrict__ rsB,
    const int* __restrict__ csB,
    const bf16_t* __restrict__ a1B, const bf16_t* __restrict__ WcB,
    const float* __restrict__ bB, void* __restrict__ oB, int Mb) {
    __shared__ char smem[A0SZ + 2 * A1SZ];

    const int tid  = threadIdx.x;
    const int wid  = tid >> 6;
    const int lane = tid & 63;
    const int quad = lane >> 4;
    const int l16  = lane & 15;

    const int side = blockIdx.x & 1;
    const int t0   = blockIdx.x >> 1;
    const int gs   = gridDim.x >> 1;       // host guarantees even grid

    const bf16_t *gsrc, *a1p; const int *rsx, *csx;
    const bf16_t* Wc; const float* bias; void* outp; int M;
    if (side == 0) { gsrc = gsA; rsx = rsA; csx = csA; a1p = a1A;
                     Wc = WcA; bias = bA; outp = oA; M = Ma; }
    else           { gsrc = gsB; rsx = rsB; csx = csB; a1p = a1B;
                     Wc = WcB; bias = bB; outp = oB; M = Mb; }
    const int nt = (M + GTILE - 1) / GTILE;
    if (t0 >= nt) return;

    // B-slice resident in registers: breg[ct][kt] = 8 bf16 at k=kt*32+quad*8 of col wid*32+ct*16+l16
    bf16x8 breg[2][8];
#pragma unroll
    for (int ct = 0; ct < 2; ++ct)
#pragma unroll
        for (int kt = 0; kt < 8; ++kt)
            breg[ct][kt] = *(const bf16x8*)(
                Wc + (size_t)(wid * 32 + ct * 16 + l16) * 256 + kt * 32 + quad * 8);

    const float bcol0 = bias[wid * 32 + l16];
    const float bcol1 = bias[wid * 32 + 16 + l16];
    const int sw = l16 & 7;

    // A1 staging decode (tile-invariant): linear LDS dest, pre-swizzled global src
    int s_row[2], s_off[2];
#pragma unroll
    for (int c = 0; c < 2; ++c) {                  // 2 calls/wave over 8KB
        int o = wid * 2048 + c * 1024 + lane * 16;
        int row = o >> 8;
        int ch  = (o >> 4) & 15;
        s_row[c] = row;
        s_off[c] = (ch ^ (row & 7)) * 8;           // bf16 elems
    }

    auto STAGE = [&](int b, int t) {
        const int r0 = t * GTILE;
        char* base = smem + A0SZ + b * A1SZ;
#pragma unroll
        for (int c = 0; c < 2; ++c) {
            int grow = r0 + s_row[c]; if (grow >= M) grow = M - 1;
            gl_lds16(a1p + (size_t)grow * DIM + s_off[c],
                     base + wid * 2048 + c * 1024);
        }
    };

    // gather: half-wave hw owns tile rows hw*4..hw*4+3, processed as 2 pairs.
    auto GATHER = [&](int t) {
        const int hw  = tid >> 5;
        const int l32 = tid & 31;
        char* a0 = smem;
#pragma unroll
        for (int pr = 0; pr < 2; ++pr) {
            const int r0 = hw * 4 + pr * 2;
            const int r1 = r0 + 1;
            const int d0 = t * GTILE + r0;
            const int d1 = t * GTILE + r1;
            int s0 = 0, n0 = 0, s1 = 0, n1 = 0;
            if (d0 < M) { s0 = rsx[d0]; n0 = rsx[d0 + 1] - s0; }
            if (d1 < M) { s1 = rsx[d1]; n1 = rsx[d1 + 1] - s1; }
            // safe clamped bases: rows with n==0 read csx[0] (valid, finite) with w=0
            const int b0 = (n0 > 0) ? s0 : 0, lim0 = (n0 > 0) ? n0 - 1 : 0;
            const int b1 = (n1 > 0) ? s1 : 0, lim1 = (n1 > 0) ? n1 - 1 : 0;
            float4 a00 = {0.f,0.f,0.f,0.f}, a01 = {0.f,0.f,0.f,0.f};
            float4 a10 = {0.f,0.f,0.f,0.f}, a11 = {0.f,0.f,0.f,0.f};
            const int nmax = max(n0, n1);
            for (int k = 0; k < nmax; k += 4) {
                int sv0[4], sv1[4];
#pragma unroll
                for (int j = 0; j < 4; ++j) {
                    sv0[j] = csx[b0 + min(k + j, lim0)];
                    sv1[j] = csx[b1 + min(k + j, lim1)];
                }
                bf16x4 v0[4], v1[4];
#pragma unroll
                for (int j = 0; j < 4; ++j)
                    v0[j] = *(const bf16x4*)(gsrc + (size_t)sv0[j] * DIM + l32 * 4);
#pragma unroll
                for (int j = 0; j < 4; ++j)
                    v1[j] = *(const bf16x4*)(gsrc + (size_t)sv1[j] * DIM + l32 * 4);
#pragma unroll
                for (int j = 0; j < 4; j += 2) {
                    float w0 = (k + j     < n0) ? 1.f : 0.f;
                    float w1 = (k + j + 1 < n0) ? 1.f : 0.f;
                    a00.x += (float)v0[j][0] * w0;     a00.y += (float)v0[j][1] * w0;
                    a00.z += (float)v0[j][2] * w0;     a00.w += (float)v0[j][3] * w0;
                    a01.x += (float)v0[j + 1][0] * w1; a01.y += (float)v0[j + 1][1] * w1;
                    a01.z += (float)v0[j + 1][2] * w1; a01.w += (float)v0[j + 1][3] * w1;
                }
#pragma unroll
                for (int j = 0; j < 4; j += 2) {
                    float w0 = (k + j     < n1) ? 1.f : 0.f;
                    float w1 = (k + j + 1 < n1) ? 1.f : 0.f;
                    a10.x += (float)v1[j][0] * w0;     a10.y += (float)v1[j][1] * w0;
                    a10.z += (float)v1[j][2] * w0;     a10.w += (float)v1[j][3] * w0;
                    a11.x += (float)v1[j + 1][0] * w1; a11.y += (float)v1[j + 1][1] * w1;
                    a11.z += (float)v1[j + 1][2] * w1; a11.w += (float)v1[j + 1][3] * w1;
                }
            }
            {
                float invn = 1.0f / (float)max(n0, 1);
                bf16x4 res;
                res[0] = (bf16_t)((a00.x + a01.x) * invn);
                res[1] = (bf16_t)((a00.y + a01.y) * invn);
                res[2] = (bf16_t)((a00.z + a01.z) * invn);
                res[3] = (bf16_t)((a00.w + a01.w) * invn);
                *(bf16x4*)(a0 + r0 * 256 + (((l32 >> 1) ^ (r0 & 7)) << 4) + ((l32 & 1) << 3)) = res;
            }
            {
                float invn = 1.0f / (float)max(n1, 1);
                bf16x4 res;
                res[0] = (bf16_t)((a10.x + a11.x) * invn);
                res[1] = (bf16_t)((a10.y + a11.y) * invn);
                res[2] = (bf16_t)((a10.z + a11.z) * invn);
                res[3] = (bf16_t)((a10.w + a11.w) * invn);
                *(bf16x4*)(a0 + r1 * 256 + (((l32 >> 1) ^ (r1 & 7)) << 4) + ((l32 & 1) << 3)) = res;
            }
        }
    };

    auto COMPUTE = [&](int b, int t) {
        const int r0 = t * GTILE;
        const char* a0base = smem;
        const char* a1base = smem + A0SZ + b * A1SZ;
        f32x4 acc[2][2];
#pragma unroll
        for (int rt = 0; rt < 2; ++rt) {
            acc[rt][0] = (f32x4){0.f, 0.f, 0.f, 0.f};
            acc[rt][1] = (f32x4){0.f, 0.f, 0.f, 0.f};
        }
#pragma unroll
        for (int rt = 0; rt < 2; ++rt) {
            const int row = rt * 16 + l16;
            bf16x8 alo[4];
#pragma unroll
            for (int kt = 0; kt < 4; ++kt)
                alo[kt] = *(const bf16x8*)(a0base + row * 256 + ((kt * 4 + quad) ^ sw) * 16);
#pragma unroll
            for (int kt = 0; kt < 4; ++kt) {
                acc[rt][0] = __builtin_amdgcn_mfma_f32_16x16x32_bf16(alo[kt], breg[0][kt], acc[rt][0], 0, 0, 0);
                acc[rt][1] = __builtin_amdgcn_mfma_f32_16x16x32_bf16(alo[kt], breg[1][kt], acc[rt][1], 0, 0, 0);
            }
#pragma unroll
            for (int kt = 0; kt < 4; ++kt) {
                bf16x8 ah = *(const bf16x8*)(a1base + row * 256 + ((kt * 4 + quad) ^ sw) * 16);
                acc[rt][0] = __builtin_amdgcn_mfma_f32_16x16x32_bf16(ah, breg[0][kt + 4], acc[rt][0], 0, 0, 0);
                acc[rt][1] = __builtin_amdgcn_mfma_f32_16x16x32_bf16(ah, breg[1][kt + 4], acc[rt][1], 0, 0, 0);
            }
        }
        // epilogue: C/D layout col = lane&15, row = quad*4 + reg
#pragma unroll
        for (int ct = 0; ct < 2; ++ct) {
            const int col = wid * 32 + ct * 16 + l16;
            const float bv = ct ? bcol1 : bcol0;
#pragma unroll
            for (int rt = 0; rt < 2; ++rt)
#pragma unroll
                for (int r = 0; r < 4; ++r) {
                    int row = r0 + rt * 16 + quad * 4 + r;
                    if (row < M) {
                        float v = acc[rt][ct][r] + bv;
                        if (MODE == 1) v = fmaxf(v, 0.f);
                        if constexpr (MODE == 2)
                            ((float*)outp)[(size_t)row * DIM + col] = v;
                        else
                            ((bf16_t*)outp)[(size_t)row * DIM + col] = (bf16_t)v;
                    }
                }
        }
    };

    STAGE(0, t0);
    int cur = 0;
    for (int t = t0; t < nt; t += gs, cur ^= 1) {
        const int nxt = t + gs;
        if (nxt < nt) STAGE(cur ^ 1, nxt);     // prefetch next A1; completes under gather
        GATHER(t);
        __syncthreads();                        // A0 + A1[cur] visible
        COMPUTE(cur, t);
        __syncthreads();                        // reads done before next overwrite
    }
}

// ---------------- launch ----------------
extern "C" void kernel_launch(void* const* d_in, const int* in_sizes, int n_in,
                              void* d_out, int out_size, void* d_ws, size_t ws_size,
                              hipStream_t stream) {
    const float* x_m = (const float*)d_in[0];
    const float* x_t = (const float*)d_in[1];
    const float* Wl  = (const float*)d_in[2];
    const float* bl  = (const float*)d_in[3];
    const float* Wr  = (const float*)d_in[4];
    const int* e_mt  = (const int*)d_in[5];
    const int* e_tm  = (const int*)d_in[6];

    const int Mm = in_sizes[0] / DIM;     // 100000
    const int Mt = in_sizes[1] / DIM;     // 100000
    const int E  = in_sizes[5] / 2;       // 400000

    float* out_m = (float*)d_out;
    float* out_t = (float*)d_out + (size_t)Mm * DIM;

    char* ws = (char*)d_ws;
    size_t off = 0;
    auto alloc = [&](size_t bytes) -> void* {
        void* p = ws + off;
        off += (bytes + 255) & ~(size_t)255;
        return p;
    };
    bf16_t* xbm    = (bf16_t*)alloc((size_t)Mm * DIM * 2);   // bf16(x_m)
    bf16_t* xbt    = (bf16_t*)alloc((size_t)Mt * DIM * 2);   // bf16(x_t)
    bf16_t* xb_m0  = (bf16_t*)alloc((size_t)Mm * DIM * 2);
    bf16_t* xb_t0  = (bf16_t*)alloc((size_t)Mt * DIM * 2);
    bf16_t* xb_m1  = (bf16_t*)alloc((size_t)Mm * DIM * 2);
    bf16_t* xb_t1  = (bf16_t*)alloc((size_t)Mt * DIM * 2);
    int*    cnt_t  = (int*)alloc((size_t)Mt * 4);
    int*    cnt_m  = (int*)alloc((size_t)Mm * 4);
    int*    rs_t   = (int*)alloc((size_t)(Mt + 1) * 4);       // M+1: rs[M]=E
    int*    rs_m   = (int*)alloc((size_t)(Mm + 1) * 4);
    int*    cur_tb = (int*)alloc((size_t)Mt * 4);
    int*    cur_mb = (int*)alloc((size_t)Mm * 4);
    int*    csr_t  = (int*)alloc((size_t)E * 4);
    int*    csr_m  = (int*)alloc((size_t)E * 4);
    bf16_t* Wc     = (bf16_t*)alloc((size_t)6 * 128 * 256 * 2);

    // ---- per-launch structure prep ----
    hipMemsetAsync(cnt_t, 0, (size_t)Mt * 4, stream);
    hipMemsetAsync(cnt_m, 0, (size_t)Mm * 4, stream);

    const int CM = Mm * DIM / 8, CT = Mt * DIM / 8;            // bf16-convert chunks
    const int PB = (6 * 128 * 256 + 255) / 256;
    const int CB = (2 * E + 255) / 256;
    const int XB = (CM + CT + 255) / 256;
    prep_count<<<PB + CB + XB, 256, 0, stream>>>(Wl, Wr, Wc,
                                                 e_mt + E, cnt_t, e_tm + E, cnt_m, E,
                                                 x_m, xbm, CM, x_t, xbt, CT, PB, CB);

    scan_all<<<2, 1024, 0, stream>>>(cnt_t, rs_t, cur_tb, Mt,
                                     cnt_m, rs_m, cur_mb, Mm);
    bin_edges2<<<(2 * E + 255) / 256, 256, 0, stream>>>(e_mt, e_mt + E, cur_tb, csr_t,
                                                        e_tm, e_tm + E, cur_mb, csr_m, E);

    // fused grid: even, persistent, sides interleaved
    int GG = 1536;
    {
        int ntT = (Mt + GTILE - 1) / GTILE, ntM = (Mm + GTILE - 1) / GTILE;
        int need = 2 * ((ntT > ntM) ? ntT : ntM);
        if (GG > need) GG = need;
        GG &= ~1;
        if (GG < 2) GG = 2;
    }

    const float* biasT0 = bl + 0 * DIM;  const float* biasM0 = bl + 1 * DIM;
    const float* biasT1 = bl + 2 * DIM;  const float* biasM1 = bl + 3 * DIM;
    const float* biasT2 = bl + 4 * DIM;  const float* biasM2 = bl + 5 * DIM;
    const bf16_t* WcT0 = Wc + 0 * 128 * 256;  const bf16_t* WcM0 = Wc + 1 * 128 * 256;
    const bf16_t* WcT1 = Wc + 2 * 128 * 256;  const bf16_t* WcM1 = Wc + 3 * 128 * 256;
    const bf16_t* WcT2 = Wc + 4 * 128 * 256;  const bf16_t* WcM2 = Wc + 5 * 128 * 256;

    // Layer 0: bf16 in, bf16 out (+relu)
    fused2<1><<<GG, 256, 0, stream>>>(
        xbm, rs_t, csr_t, xbt, WcT0, biasT0, xb_t0, Mt,
        xbt, rs_m, csr_m, xbm, WcM0, biasM0, xb_m0, Mm);
    // Layer 1: bf16 in, bf16 out (+relu)
    fused2<1><<<GG, 256, 0, stream>>>(
        xb_m0, rs_t, csr_t, xb_t0, WcT1, biasT1, xb_t1, Mt,
        xb_t0, rs_m, csr_m, xb_m0, WcM1, biasM1, xb_m1, Mm);
    // Layer 2: bf16 in, f32 out, no relu
    fused2<2><<<GG, 256, 0, stream>>>(
        xb_m1, rs_t, csr_t, xb_t1, WcT2, biasT2, out_t, Mt,
        xb_t1, rs_m, csr_m, xb_m1, WcM2, biasM2, out_m, Mm);
}

// Round 9
// 503.237 us; speedup vs baseline: 1.1811x; 1.1811x over previous
//
#include <hip/hip_runtime.h>
#include <hip/hip_bf16.h>

typedef __bf16 bf16_t;
typedef __attribute__((ext_vector_type(4))) __bf16 bf16x4;
typedef __attribute__((ext_vector_type(8))) __bf16 bf16x8;
typedef __attribute__((ext_vector_type(4))) float f32x4;

#define DIM 128
#define GTILE 32

// async global->LDS, 16B per lane. LDS dest = wave-uniform base + lane*16.
__device__ __forceinline__ void gl_lds16(const void* g, void* l) {
    __builtin_amdgcn_global_load_lds(
        (const __attribute__((address_space(1))) unsigned int*)g,
        (__attribute__((address_space(3))) unsigned int*)l, 16, 0, 0);
}

// ---- merged weight-prep + degree count + f32->bf16 input convert (independent) ----
__global__ void prep_count(const float* __restrict__ Wl, const float* __restrict__ Wr,
                           bf16_t* __restrict__ Wc,
                           const int* __restrict__ dA, int* __restrict__ cA,
                           const int* __restrict__ dB, int* __restrict__ cB, int E,
                           const float* __restrict__ xm, bf16_t* __restrict__ xbm, int CM,
                           const float* __restrict__ xt, bf16_t* __restrict__ xbt, int CT,
                           int PB, int CB) {
    int blk = blockIdx.x;
    if (blk < PB) {
        int idx = blk * 256 + threadIdx.x;           // over 6*128*256
        if (idx >= 6 * 128 * 256) return;
        int k = idx & 255;
        int n = (idx >> 8) & 127;
        int s = idx >> 15;                            // 0..5
        float v;
        if (k < 128) v = Wl[((size_t)s * 128 + n) * 128 + k];
        else         v = Wr[((size_t)s * 128 + n) * 128 + (k - 128)];
        Wc[idx] = (bf16_t)v;
    } else if (blk < PB + CB) {
        int i = (blk - PB) * 256 + threadIdx.x;
        if (i < E) atomicAdd(&cA[dA[i]], 1);
        else if (i < 2 * E) atomicAdd(&cB[dB[i - E]], 1);
    } else {
        int i = (blk - PB - CB) * 256 + threadIdx.x;  // chunk of 8 elems
        const float* src; bf16_t* dst;
        if (i < CM) { src = xm; dst = xbm; }
        else if ((i -= CM) < CT) { src = xt; dst = xbt; }
        else return;
        float4 a = ((const float4*)src)[(size_t)i * 2];
        float4 b = ((const float4*)src)[(size_t)i * 2 + 1];
        bf16x8 r;
        r[0] = (bf16_t)a.x; r[1] = (bf16_t)a.y; r[2] = (bf16_t)a.z; r[3] = (bf16_t)a.w;
        r[4] = (bf16_t)b.x; r[5] = (bf16_t)b.y; r[6] = (bf16_t)b.z; r[7] = (bf16_t)b.w;
        *(bf16x8*)(dst + (size_t)i * 8) = r;
    }
}

// ---------------- CSR build: parallel 3-stage scan (proven, ~12us total) --------
__global__ __launch_bounds__(256) void scan_local2(
    const int* __restrict__ cntA, int* __restrict__ partA, int* __restrict__ bsumA,
    int MA, int NBA,
    const int* __restrict__ cntB, int* __restrict__ partB, int* __restrict__ bsumB,
    int MB) {
    int blk = blockIdx.x;
    const int* cnt; int* partial; int* blocksum; int M; int b;
    if (blk < NBA) { cnt = cntA; partial = partA; blocksum = bsumA; M = MA; b = blk; }
    else           { cnt = cntB; partial = partB; blocksum = bsumB; M = MB; b = blk - NBA; }
    __shared__ int sdata[256];
    int i = b * 256 + threadIdx.x;
    int v = (i < M) ? cnt[i] : 0;
    sdata[threadIdx.x] = v;
    __syncthreads();
    for (int off = 1; off < 256; off <<= 1) {
        int t = (threadIdx.x >= off) ? sdata[threadIdx.x - off] : 0;
        __syncthreads();
        sdata[threadIdx.x] += t;
        __syncthreads();
    }
    int incl = sdata[threadIdx.x];
    if (i < M) partial[i] = incl - v;
    if (threadIdx.x == 255) blocksum[b] = incl;
}

__global__ __launch_bounds__(256) void scan_blocks2(int* __restrict__ bsA, int NA,
                                                    int* __restrict__ bsB, int NBcnt) {
    int* blocksum = blockIdx.x ? bsB : bsA;
    int NB = blockIdx.x ? NBcnt : NA;
    __shared__ int sdata[256];
    __shared__ int running;
    if (threadIdx.x == 0) running = 0;
    __syncthreads();
    for (int base = 0; base < NB; base += 256) {
        int i = base + threadIdx.x;
        int v = (i < NB) ? blocksum[i] : 0;
        sdata[threadIdx.x] = v;
        __syncthreads();
        for (int off = 1; off < 256; off <<= 1) {
            int t = (threadIdx.x >= off) ? sdata[threadIdx.x - off] : 0;
            __syncthreads();
            sdata[threadIdx.x] += t;
            __syncthreads();
        }
        int incl = sdata[threadIdx.x];
        int r = running;
        __syncthreads();
        if (i < NB) blocksum[i] = incl - v + r;
        if (threadIdx.x == 0) running = r + sdata[255];
        __syncthreads();
    }
}

// also writes rs[M] = E so fused2 can use rs[d+1]-rs[d] as the degree.
__global__ __launch_bounds__(256) void add_offsets2(
    const int* __restrict__ pA, const int* __restrict__ bsA,
    int* __restrict__ rsA, int* __restrict__ curA, int MA, int NBA,
    const int* __restrict__ pB, const int* __restrict__ bsB,
    int* __restrict__ rsB, int* __restrict__ curB, int MB, int E) {
    if (blockIdx.x == 0 && threadIdx.x == 0) { rsA[MA] = E; rsB[MB] = E; }
    int blk = blockIdx.x;
    const int *partial, *blocksum; int *rowstart, *cursor; int M, b;
    if (blk < NBA) { partial = pA; blocksum = bsA; rowstart = rsA; cursor = curA; M = MA; b = blk; }
    else           { partial = pB; blocksum = bsB; rowstart = rsB; cursor = curB; M = MB; b = blk - NBA; }
    int i = b * 256 + threadIdx.x;
    if (i < M) {
        int rs = partial[i] + blocksum[i >> 8];
        rowstart[i] = rs;
        cursor[i] = rs;
    }
}

__global__ void bin_edges2(const int* __restrict__ sA, const int* __restrict__ dA,
                           int* __restrict__ curA, int* __restrict__ csrA,
                           const int* __restrict__ sB, const int* __restrict__ dB,
                           int* __restrict__ curB, int* __restrict__ csrB, int E) {
    int e = blockIdx.x * blockDim.x + threadIdx.x;
    if (e < E) {
        int d = dA[e];
        int pos = atomicAdd(&curA[d], 1);
        csrA[pos] = sA[e];
    } else if (e < 2 * E) {
        int i = e - E;
        int d = dB[i];
        int pos = atomicAdd(&curB[d], 1);
        csrB[pos] = sB[i];
    }
}

// ---------------- fused gather-mean + GEMM, persistent, both sides --------------
// All inputs bf16. Per 32-row tile: gather phase computes mean of neighbor bf16
// rows (f32 accumulate) directly into the swizzled A0 LDS buffer; A1 (x_dst,
// bf16) prefetched via global_load_lds double-buffer (hidden under gather);
// then MFMA: out = A0@Wl.T + bias + A1@Wr.T (+ReLU).
// MODE 1: out bf16 + relu.  MODE 2: out f32, no relu.
// Gather: rows processed in PAIRS with exact batch-4 per row (8 independent
// loads in flight). Per-row summation order (even k->acc0, odd k->acc1,
// ascending) is bit-identical to the original. Degree n = rs[d+1]-rs[d].
// __launch_bounds__(256,3): (256,5) proved to spill breg (round 6, +236MB HBM).
#define A0SZ 8192               // 32 rows * 256B bf16
#define A1SZ 8192               // 32 rows * 256B bf16

template <int MODE>
__global__ __launch_bounds__(256, 3) void fused2(
    const bf16_t* __restrict__ gsA, const int* __restrict__ rsA,
    const int* __restrict__ csA,
    const bf16_t* __restrict__ a1A, const bf16_t* __restrict__ WcA,
    const float* __restrict__ bA, void* __restrict__ oA, int Ma,
    const bf16_t* __restrict__ gsB, const int* __restrict__ rsB,
    const int* __restrict__ csB,
    const bf16_t* __restrict__ a1B, const bf16_t* __restrict__ WcB,
    const float* __restrict__ bB, void* __restrict__ oB, int Mb) {
    __shared__ char smem[A0SZ + 2 * A1SZ];

    const int tid  = threadIdx.x;
    const int wid  = tid >> 6;
    const int lane = tid & 63;
    const int quad = lane >> 4;
    const int l16  = lane & 15;

    const int side = blockIdx.x & 1;
    const int t0   = blockIdx.x >> 1;
    const int gs   = gridDim.x >> 1;       // host guarantees even grid

    const bf16_t *gsrc, *a1p; const int *rsx, *csx;
    const bf16_t* Wc; const float* bias; void* outp; int M;
    if (side == 0) { gsrc = gsA; rsx = rsA; csx = csA; a1p = a1A;
                     Wc = WcA; bias = bA; outp = oA; M = Ma; }
    else           { gsrc = gsB; rsx = rsB; csx = csB; a1p = a1B;
                     Wc = WcB; bias = bB; outp = oB; M = Mb; }
    const int nt = (M + GTILE - 1) / GTILE;
    if (t0 >= nt) return;

    // B-slice resident in registers: breg[ct][kt] = 8 bf16 at k=kt*32+quad*8 of col wid*32+ct*16+l16
    bf16x8 breg[2][8];
#pragma unroll
    for (int ct = 0; ct < 2; ++ct)
#pragma unroll
        for (int kt = 0; kt < 8; ++kt)
            breg[ct][kt] = *(const bf16x8*)(
                Wc + (size_t)(wid * 32 + ct * 16 + l16) * 256 + kt * 32 + quad * 8);

    const float bcol0 = bias[wid * 32 + l16];
    const float bcol1 = bias[wid * 32 + 16 + l16];
    const int sw = l16 & 7;

    // A1 staging decode (tile-invariant): linear LDS dest, pre-swizzled global src
    int s_row[2], s_off[2];
#pragma unroll
    for (int c = 0; c < 2; ++c) {                  // 2 calls/wave over 8KB
        int o = wid * 2048 + c * 1024 + lane * 16;
        int row = o >> 8;
        int ch  = (o >> 4) & 15;
        s_row[c] = row;
        s_off[c] = (ch ^ (row & 7)) * 8;           // bf16 elems
    }

    auto STAGE = [&](int b, int t) {
        const int r0 = t * GTILE;
        char* base = smem + A0SZ + b * A1SZ;
#pragma unroll
        for (int c = 0; c < 2; ++c) {
            int grow = r0 + s_row[c]; if (grow >= M) grow = M - 1;
            gl_lds16(a1p + (size_t)grow * DIM + s_off[c],
                     base + wid * 2048 + c * 1024);
        }
    };

    // gather: half-wave hw owns tile rows hw*4..hw*4+3, processed as 2 pairs.
    auto GATHER = [&](int t) {
        const int hw  = tid >> 5;
        const int l32 = tid & 31;
        char* a0 = smem;
#pragma unroll
        for (int pr = 0; pr < 2; ++pr) {
            const int r0 = hw * 4 + pr * 2;
            const int r1 = r0 + 1;
            const int d0 = t * GTILE + r0;
            const int d1 = t * GTILE + r1;
            int s0 = 0, n0 = 0, s1 = 0, n1 = 0;
            if (d0 < M) { s0 = rsx[d0]; n0 = rsx[d0 + 1] - s0; }
            if (d1 < M) { s1 = rsx[d1]; n1 = rsx[d1 + 1] - s1; }
            // safe clamped bases: rows with n==0 read csx[0] (valid, finite) with w=0
            const int b0 = (n0 > 0) ? s0 : 0, lim0 = (n0 > 0) ? n0 - 1 : 0;
            const int b1 = (n1 > 0) ? s1 : 0, lim1 = (n1 > 0) ? n1 - 1 : 0;
            float4 a00 = {0.f,0.f,0.f,0.f}, a01 = {0.f,0.f,0.f,0.f};
            float4 a10 = {0.f,0.f,0.f,0.f}, a11 = {0.f,0.f,0.f,0.f};
            const int nmax = max(n0, n1);
            for (int k = 0; k < nmax; k += 4) {
                int sv0[4], sv1[4];
#pragma unroll
                for (int j = 0; j < 4; ++j) {
                    sv0[j] = csx[b0 + min(k + j, lim0)];
                    sv1[j] = csx[b1 + min(k + j, lim1)];
                }
                bf16x4 v0[4], v1[4];
#pragma unroll
                for (int j = 0; j < 4; ++j)
                    v0[j] = *(const bf16x4*)(gsrc + (size_t)sv0[j] * DIM + l32 * 4);
#pragma unroll
                for (int j = 0; j < 4; ++j)
                    v1[j] = *(const bf16x4*)(gsrc + (size_t)sv1[j] * DIM + l32 * 4);
#pragma unroll
                for (int j = 0; j < 4; j += 2) {
                    float w0 = (k + j     < n0) ? 1.f : 0.f;
                    float w1 = (k + j + 1 < n0) ? 1.f : 0.f;
                    a00.x += (float)v0[j][0] * w0;     a00.y += (float)v0[j][1] * w0;
                    a00.z += (float)v0[j][2] * w0;     a00.w += (float)v0[j][3] * w0;
                    a01.x += (float)v0[j + 1][0] * w1; a01.y += (float)v0[j + 1][1] * w1;
                    a01.z += (float)v0[j + 1][2] * w1; a01.w += (float)v0[j + 1][3] * w1;
                }
#pragma unroll
                for (int j = 0; j < 4; j += 2) {
                    float w0 = (k + j     < n1) ? 1.f : 0.f;
                    float w1 = (k + j + 1 < n1) ? 1.f : 0.f;
                    a10.x += (float)v1[j][0] * w0;     a10.y += (float)v1[j][1] * w0;
                    a10.z += (float)v1[j][2] * w0;     a10.w += (float)v1[j][3] * w0;
                    a11.x += (float)v1[j + 1][0] * w1; a11.y += (float)v1[j + 1][1] * w1;
                    a11.z += (float)v1[j + 1][2] * w1; a11.w += (float)v1[j + 1][3] * w1;
                }
            }
            {
                float invn = 1.0f / (float)max(n0, 1);
                bf16x4 res;
                res[0] = (bf16_t)((a00.x + a01.x) * invn);
                res[1] = (bf16_t)((a00.y + a01.y) * invn);
                res[2] = (bf16_t)((a00.z + a01.z) * invn);
                res[3] = (bf16_t)((a00.w + a01.w) * invn);
                *(bf16x4*)(a0 + r0 * 256 + (((l32 >> 1) ^ (r0 & 7)) << 4) + ((l32 & 1) << 3)) = res;
            }
            {
                float invn = 1.0f / (float)max(n1, 1);
                bf16x4 res;
                res[0] = (bf16_t)((a10.x + a11.x) * invn);
                res[1] = (bf16_t)((a10.y + a11.y) * invn);
                res[2] = (bf16_t)((a10.z + a11.z) * invn);
                res[3] = (bf16_t)((a10.w + a11.w) * invn);
                *(bf16x4*)(a0 + r1 * 256 + (((l32 >> 1) ^ (r1 & 7)) << 4) + ((l32 & 1) << 3)) = res;
            }
        }
    };

    auto COMPUTE = [&](int b, int t) {
        const int r0 = t * GTILE;
        const char* a0base = smem;
        const char* a1base = smem + A0SZ + b * A1SZ;
        f32x4 acc[2][2];
#pragma unroll
        for (int rt = 0; rt < 2; ++rt) {
            acc[rt][0] = (f32x4){0.f, 0.f, 0.f, 0.f};
            acc[rt][1] = (f32x4){0.f, 0.f, 0.f, 0.f};
        }
#pragma unroll
        for (int rt = 0; rt < 2; ++rt) {
            const int row = rt * 16 + l16;
            bf16x8 alo[4];
#pragma unroll
            for (int kt = 0; kt < 4; ++kt)
                alo[kt] = *(const bf16x8*)(a0base + row * 256 + ((kt * 4 + quad) ^ sw) * 16);
#pragma unroll
            for (int kt = 0; kt < 4; ++kt) {
                acc[rt][0] = __builtin_amdgcn_mfma_f32_16x16x32_bf16(alo[kt], breg[0][kt], acc[rt][0], 0, 0, 0);
                acc[rt][1] = __builtin_amdgcn_mfma_f32_16x16x32_bf16(alo[kt], breg[1][kt], acc[rt][1], 0, 0, 0);
            }
#pragma unroll
            for (int kt = 0; kt < 4; ++kt) {
                bf16x8 ah = *(const bf16x8*)(a1base + row * 256 + ((kt * 4 + quad) ^ sw) * 16);
                acc[rt][0] = __builtin_amdgcn_mfma_f32_16x16x32_bf16(ah, breg[0][kt + 4], acc[rt][0], 0, 0, 0);
                acc[rt][1] = __builtin_amdgcn_mfma_f32_16x16x32_bf16(ah, breg[1][kt + 4], acc[rt][1], 0, 0, 0);
            }
        }
        // epilogue: C/D layout col = lane&15, row = quad*4 + reg
#pragma unroll
        for (int ct = 0; ct < 2; ++ct) {
            const int col = wid * 32 + ct * 16 + l16;
            const float bv = ct ? bcol1 : bcol0;
#pragma unroll
            for (int rt = 0; rt < 2; ++rt)
#pragma unroll
                for (int r = 0; r < 4; ++r) {
                    int row = r0 + rt * 16 + quad * 4 + r;
                    if (row < M) {
                        float v = acc[rt][ct][r] + bv;
                        if (MODE == 1) v = fmaxf(v, 0.f);
                        if constexpr (MODE == 2)
                            ((float*)outp)[(size_t)row * DIM + col] = v;
                        else
                            ((bf16_t*)outp)[(size_t)row * DIM + col] = (bf16_t)v;
                    }
                }
        }
    };

    STAGE(0, t0);
    int cur = 0;
    for (int t = t0; t < nt; t += gs, cur ^= 1) {
        const int nxt = t + gs;
        if (nxt < nt) STAGE(cur ^ 1, nxt);     // prefetch next A1; completes under gather
        GATHER(t);
        __syncthreads();                        // A0 + A1[cur] visible
        COMPUTE(cur, t);
        __syncthreads();                        // reads done before next overwrite
    }
}

// ---------------- launch ----------------
extern "C" void kernel_launch(void* const* d_in, const int* in_sizes, int n_in,
                              void* d_out, int out_size, void* d_ws, size_t ws_size,
                              hipStream_t stream) {
    const float* x_m = (const float*)d_in[0];
    const float* x_t = (const float*)d_in[1];
    const float* Wl  = (const float*)d_in[2];
    const float* bl  = (const float*)d_in[3];
    const float* Wr  = (const float*)d_in[4];
    const int* e_mt  = (const int*)d_in[5];
    const int* e_tm  = (const int*)d_in[6];

    const int Mm = in_sizes[0] / DIM;     // 100000
    const int Mt = in_sizes[1] / DIM;     // 100000
    const int E  = in_sizes[5] / 2;       // 400000
    const int NBt = (Mt + 255) / 256;
    const int NBm = (Mm + 255) / 256;

    float* out_m = (float*)d_out;
    float* out_t = (float*)d_out + (size_t)Mm * DIM;

    char* ws = (char*)d_ws;
    size_t off = 0;
    auto alloc = [&](size_t bytes) -> void* {
        void* p = ws + off;
        off += (bytes + 255) & ~(size_t)255;
        return p;
    };
    bf16_t* xbm    = (bf16_t*)alloc((size_t)Mm * DIM * 2);   // bf16(x_m)
    bf16_t* xbt    = (bf16_t*)alloc((size_t)Mt * DIM * 2);   // bf16(x_t)
    bf16_t* xb_m0  = (bf16_t*)alloc((size_t)Mm * DIM * 2);
    bf16_t* xb_t0  = (bf16_t*)alloc((size_t)Mt * DIM * 2);
    bf16_t* xb_m1  = (bf16_t*)alloc((size_t)Mm * DIM * 2);
    bf16_t* xb_t1  = (bf16_t*)alloc((size_t)Mt * DIM * 2);
    int*    cnt_t  = (int*)alloc((size_t)Mt * 4);
    int*    cnt_m  = (int*)alloc((size_t)Mm * 4);
    int*    rs_t   = (int*)alloc((size_t)(Mt + 1) * 4);       // M+1: rs[M]=E
    int*    rs_m   = (int*)alloc((size_t)(Mm + 1) * 4);
    int*    cur_tb = (int*)alloc((size_t)Mt * 4);
    int*    cur_mb = (int*)alloc((size_t)Mm * 4);
    int*    part_t = (int*)alloc((size_t)Mt * 4);
    int*    part_m = (int*)alloc((size_t)Mm * 4);
    int*    bsum_t = (int*)alloc((size_t)NBt * 4);
    int*    bsum_m = (int*)alloc((size_t)NBm * 4);
    int*    csr_t  = (int*)alloc((size_t)E * 4);
    int*    csr_m  = (int*)alloc((size_t)E * 4);
    bf16_t* Wc     = (bf16_t*)alloc((size_t)6 * 128 * 256 * 2);

    // ---- per-launch structure prep ----
    hipMemsetAsync(cnt_t, 0, (size_t)Mt * 4, stream);
    hipMemsetAsync(cnt_m, 0, (size_t)Mm * 4, stream);

    const int CM = Mm * DIM / 8, CT = Mt * DIM / 8;            // bf16-convert chunks
    const int PB = (6 * 128 * 256 + 255) / 256;
    const int CB = (2 * E + 255) / 256;
    const int XB = (CM + CT + 255) / 256;
    prep_count<<<PB + CB + XB, 256, 0, stream>>>(Wl, Wr, Wc,
                                                 e_mt + E, cnt_t, e_tm + E, cnt_m, E,
                                                 x_m, xbm, CM, x_t, xbt, CT, PB, CB);

    scan_local2<<<NBt + NBm, 256, 0, stream>>>(cnt_t, part_t, bsum_t, Mt, NBt,
                                               cnt_m, part_m, bsum_m, Mm);
    scan_blocks2<<<2, 256, 0, stream>>>(bsum_t, NBt, bsum_m, NBm);
    add_offsets2<<<NBt + NBm, 256, 0, stream>>>(part_t, bsum_t, rs_t, cur_tb, Mt, NBt,
                                                part_m, bsum_m, rs_m, cur_mb, Mm, E);
    bin_edges2<<<(2 * E + 255) / 256, 256, 0, stream>>>(e_mt, e_mt + E, cur_tb, csr_t,
                                                        e_tm, e_tm + E, cur_mb, csr_m, E);

    // fused grid: even, persistent, sides interleaved
    int GG = 1536;
    {
        int ntT = (Mt + GTILE - 1) / GTILE, ntM = (Mm + GTILE - 1) / GTILE;
        int need = 2 * ((ntT > ntM) ? ntT : ntM);
        if (GG > need) GG = need;
        GG &= ~1;
        if (GG < 2) GG = 2;
    }

    const float* biasT0 = bl + 0 * DIM;  const float* biasM0 = bl + 1 * DIM;
    const float* biasT1 = bl + 2 * DIM;  const float* biasM1 = bl + 3 * DIM;
    const float* biasT2 = bl + 4 * DIM;  const float* biasM2 = bl + 5 * DIM;
    const bf16_t* WcT0 = Wc + 0 * 128 * 256;  const bf16_t* WcM0 = Wc + 1 * 128 * 256;
    const bf16_t* WcT1 = Wc + 2 * 128 * 256;  const bf16_t* WcM1 = Wc + 3 * 128 * 256;
    const bf16_t* WcT2 = Wc + 4 * 128 * 256;  const bf16_t* WcM2 = Wc + 5 * 128 * 256;

    // Layer 0: bf16 in, bf16 out (+relu)
    fused2<1><<<GG, 256, 0, stream>>>(
        xbm, rs_t, csr_t, xbt, WcT0, biasT0, xb_t0, Mt,
        xbt, rs_m, csr_m, xbm, WcM0, biasM0, xb_m0, Mm);
    // Layer 1: bf16 in, bf16 out (+relu)
    fused2<1><<<GG, 256, 0, stream>>>(
        xb_m0, rs_t, csr_t, xb_t0, WcT1, biasT1, xb_t1, Mt,
        xb_t0, rs_m, csr_m, xb_m0, WcM1, biasM1, xb_m1, Mm);
    // Layer 2: bf16 in, f32 out, no relu
    fused2<2><<<GG, 256, 0, stream>>>(
        xb_m1, rs_t, csr_t, xb_t1, WcT2, biasT2, out_t, Mt,
        xb_t1, rs_m, csr_m, xb_m1, WcM2, biasM2, out_m, Mm);
}